// Round 3
// baseline (507.343 us; speedup 1.0000x reference)
//
#include <hip/hip_runtime.h>
#include <math.h>

#define NPTS 8192
#define NB 2
#define NROWS (NB * NPTS)
#define KNN 16
#define KC 6          // per-lane kept candidates (truncated sorted list)

// Spatial grid: 32^3 cells of width H. 4 grids: P/T x batch. g: P=2b, T=2b+1.
#define GRID 32
#define NCELLS (GRID * GRID * GRID)        // 32768
#define TOTCELLS (4 * NCELLS)              // 131072
#define H 0.35f
#define RLO (-5.6f)
#define INVH (1.0f / H)
#define SCAN_BLOCKS 128
#define SEGCAP 132                          // >= 2*64 segments per row-chunk

// Cell-centric query scheme: queries sharing a cell share one enumeration,
// and candidate POINTS are staged in LDS (scan is pure-LDS). QC queries per
// work item; CAP points per wave; stop when >= NEED candidates after shell
// m>=1 (NEED2 for min-only task 2). Overflow (>CAP) -> exact repair path.
#define QC 8
#define CAP 512
#define NEED 192
#define NEED2 32
#define WLCAP 49152     // max worklist entries: 2*8192(T)*2 + 8192(P)*2

__device__ __forceinline__ int cellof(float x) {
  int c = (int)floorf((x - RLO) * INVH);
  return min(max(c, 0), GRID - 1);
}

__device__ __forceinline__ float sqd3(float qx, float qy, float qz, float4 c) {
  float dx = qx - c.x, dy = qy - c.y, dz = qz - c.z;
  return fmaf(dx, dx, fmaf(dy, dy, dz * dz));
}

__device__ __forceinline__ int lanerank(unsigned long long mk) {
  return __builtin_amdgcn_mbcnt_hi((unsigned)(mk >> 32),
                                   __builtin_amdgcn_mbcnt_lo((unsigned)mk, 0));
}

// Guarded insert into ascending sorted-K list (per-lane).
template <int K>
__device__ __forceinline__ void insertK(float (&a)[K], float d) {
  if (d < a[K - 1]) {
    a[K - 1] = d;
#pragma unroll
    for (int k = K - 1; k > 0; --k) {
      float lo = fminf(a[k - 1], a[k]);
      a[k] = fmaxf(a[k - 1], a[k]);
      a[k - 1] = lo;
    }
  }
}

// Full ascending bitonic sort of one value per lane across the 64-lane wave.
__device__ __forceinline__ float bitonic_sort64(float v, int lane) {
#pragma unroll
  for (int k = 2; k <= 64; k <<= 1) {
#pragma unroll
    for (int j = k >> 1; j >= 1; j >>= 1) {
      float o = __shfl_xor(v, j, 64);
      bool up = ((lane & k) == 0);
      bool lower = ((lane & j) == 0);
      float mn = fminf(v, o), mx = fmaxf(v, o);
      v = (up == lower) ? mn : mx;
    }
  }
  return v;
}

// Per-query exact-stop wave kNN (Round-0 verified code): expanding Chebyshev
// shells, stop when >= NEED kept candidates lie within the proven bound.
// Used by repair_kernel for rows the shared-enumeration path flagged.
template <int K, int NEEDQ>
__device__ void wave_grid_knn_pq(int g, float qx, float qy, float qz,
                                 const float4* __restrict__ sorted,
                                 const unsigned* __restrict__ pack,
                                 unsigned* sS, unsigned* sC, unsigned* sPre,
                                 int lane, float (&a)[K], float& dmin,
                                 int& cnt, float& bnd2) {
  const int cx = cellof(qx), cy = cellof(qy), cz = cellof(qz);
  float fx = fminf(qx - (RLO + cx * H), (RLO + (cx + 1) * H) - qx);
  float fy = fminf(qy - (RLO + cy * H), (RLO + (cy + 1) * H) - qy);
  float fz = fminf(qz - (RLO + cz * H), (RLO + (cz + 1) * H) - qz);
  const float fq = fminf(fx, fminf(fy, fz));   // may be <0 for clamped queries
  const int base = g * NCELLS;
  for (int m = 0; m <= GRID; ++m) {
    const int zlo = max(cz - m, 0), zhi = min(cz + m, GRID - 1);
    const int ylo = max(cy - m, 0), yhi = min(cy + m, GRID - 1);
    const int xlo = max(cx - m, 0), xhi = min(cx + m, GRID - 1);
    const int ny = yhi - ylo + 1;
    const int nrows = (zhi - zlo + 1) * ny;
    for (int rb = 0; rb < nrows; rb += 64) {
      const int rho = rb + lane;
      const bool act = rho < nrows;
      const int rr = act ? rho : 0;
      const int z = zlo + rr / ny, y = ylo + rr % ny;
      const int dza = abs(z - cz), dya = abs(y - cy);
      const bool bdry = (dza == m) || (dya == m);
      unsigned stA = 0, cnA = 0, stB = 0, cnB = 0;
      const int rowbase = base + (z * GRID + y) * GRID;
      if (act) {
        if (bdry) {
          unsigned plo = pack[rowbase + xlo];
          unsigned phi = pack[rowbase + xhi];
          stA = plo >> 14;
          cnA = ((phi >> 14) + (phi & 16383u)) - stA;
        } else {
          int xl = cx - m, xr = cx + m;
          if (xl >= 0) { unsigned p = pack[rowbase + xl]; stA = p >> 14; cnA = p & 16383u; }
          if (xr < GRID) { unsigned p = pack[rowbase + xr]; stB = p >> 14; cnB = p & 16383u; }
        }
      }
      unsigned long long mA = __ballot(cnA > 0);
      unsigned long long mB = __ballot(cnB > 0);
      int nA = __popcll(mA);
      int nseg = nA + __popcll(mB);
      if (nseg == 0) continue;
      int slA = lanerank(mA), slB = nA + lanerank(mB);
      if (cnA > 0) { sS[slA] = stA; sC[slA] = cnA; }
      if (cnB > 0) { sS[slB] = stB; sC[slB] = cnB; }
      unsigned total = 0;
      for (int h = 0; h < 2; ++h) {
        int sl = h * 64 + lane;
        unsigned v = (sl < nseg) ? sC[sl] : 0u;
        unsigned inc = v;
#pragma unroll
        for (int s2 = 1; s2 < 64; s2 <<= 1) {
          unsigned t = __shfl_up(inc, s2, 64);
          if (lane >= s2) inc += t;
        }
        if (sl < nseg) sPre[sl] = total + inc - v;
        total += __shfl(inc, 63, 64);
        if (nseg <= 64) break;
      }
      int sh0 = (nseg > 1) ? (1 << (31 - __clz(nseg - 1))) : 0;
      for (unsigned cb = 0; cb < total; cb += 64) {
        unsigned c = cb + (unsigned)lane;
        bool cact = c < total;
        unsigned cc = cact ? c : (total - 1);
        int lo = 0;
        for (int sh = sh0; sh; sh >>= 1) {
          int mid = lo + sh;
          if (mid < nseg && sPre[mid] <= cc) lo = mid;
        }
        float4 p = sorted[sS[lo] + (cc - sPre[lo])];
        float d = cact ? sqd3(qx, qy, qz, p) : INFINITY;
        dmin = fminf(dmin, fmaxf(d, a[K - 1]));
        insertK(a, d);
      }
    }
    float bnd = fmaxf((float)m * H + fq, 0.0f) * 0.999f;
    bnd2 = bnd * bnd;
    int c = 0;
#pragma unroll
    for (int k = 0; k < K; ++k) c += (a[k] <= bnd2) ? 1 : 0;
#pragma unroll
    for (int s2 = 1; s2 < 64; s2 <<= 1) c += __shfl_xor(c, s2, 64);
    cnt = c;
    bool covered = (zlo == 0 && zhi == GRID - 1 && ylo == 0 && yhi == GRID - 1 &&
                    xlo == 0 && xhi == GRID - 1);
    if (c >= NEEDQ || covered) break;
  }
}

// ---------- build ----------
__global__ __launch_bounds__(256) void count_kernel(
    const float* __restrict__ yp, const float* __restrict__ yt,
    unsigned* __restrict__ counts, int* __restrict__ pflat,
    unsigned* __restrict__ prank, unsigned* __restrict__ wcnt) {
  // wcnt: [4]=worklist count, [5]=work claim, [6]=repair count, [7]=repair claim
  if (blockIdx.x == 0 && threadIdx.x < 8) wcnt[threadIdx.x] = 0;
  int t = blockIdx.x * 256 + threadIdx.x;          // 0 .. 2*NROWS-1
  const float* src;
  int g;
  if (t < NROWS) { src = yp + 3 * t; g = 2 * (t >> 13); }
  else { int u = t - NROWS; src = yt + 3 * u; g = 2 * (u >> 13) + 1; }
  int flat = g * NCELLS + (cellof(src[2]) * GRID + cellof(src[1])) * GRID + cellof(src[0]);
  unsigned r = atomicAdd(&counts[flat], 1u);
  pflat[t] = flat;
  prank[t] = r;
}

__global__ __launch_bounds__(1024) void scan1_kernel(
    const unsigned* __restrict__ counts, unsigned* __restrict__ partial,
    unsigned* __restrict__ aux) {
  __shared__ unsigned ws[16];
  const int t = threadIdx.x, lane = t & 63, wave = t >> 6;
  const int tid = blockIdx.x * 1024 + t;
  unsigned v = counts[tid];
  unsigned inc = v;
#pragma unroll
  for (int off = 1; off < 64; off <<= 1) {
    unsigned u = __shfl_up(inc, off, 64);
    if (lane >= off) inc += u;
  }
  if (lane == 63) ws[wave] = inc;
  __syncthreads();
  unsigned wex = 0;
  if (wave == 0) {
    unsigned o = (lane < 16) ? ws[lane] : 0u;
    unsigned wi = o;
#pragma unroll
    for (int off = 1; off < 16; off <<= 1) {
      unsigned u = __shfl_up(wi, off, 64);
      if (lane >= off) wi += u;
    }
    if (lane < 16) ws[lane] = wi - o;
  }
  __syncthreads();
  wex = ws[wave];
  partial[tid] = wex + inc - v;
  if (t == 1023) aux[blockIdx.x] = wex + inc;
}

// Fused scan2+pack + flat (batch,task,cell,chunk) worklist build.
// cellinfo pack: global start (<=16b used of 18) << 14 | count (14b)
// worklist entry: b<<28 | task<<26 | cell<<11 | chunk_j (j <= 2047)
__global__ __launch_bounds__(1024) void pack_kernel(
    const unsigned* __restrict__ counts, const unsigned* __restrict__ partial,
    const unsigned* __restrict__ aux, unsigned* __restrict__ pack,
    unsigned* __restrict__ wcnt, unsigned* __restrict__ wlist) {
  __shared__ unsigned sa[2];
  const int t = threadIdx.x;
  if (t < 128) {
    unsigned v = (t < (int)blockIdx.x) ? aux[t] : 0u;
#pragma unroll
    for (int s = 1; s < 64; s <<= 1) v += __shfl_xor(v, s, 64);
    if ((t & 63) == 0) sa[t >> 6] = v;
  }
  __syncthreads();
  unsigned base = sa[0] + sa[1];
  int i = blockIdx.x * 1024 + t;
  unsigned cnti = counts[i];
  pack[i] = ((partial[i] + base) << 14) | cnti;
  if (cnti > 0) {
    int g = i >> 15;                 // NCELLS = 2^15
    unsigned b = (unsigned)(g >> 1);
    unsigned cellw = (unsigned)(i & (NCELLS - 1));
    unsigned nch = (cnti + QC - 1) / QC;     // <= 2048
    if (g & 1) {     // T grid: tasks 0 (vs P) and 1 (vs T)
      unsigned slot = atomicAdd(&wcnt[4], 2 * nch);
      for (unsigned j = 0; j < nch; ++j) {
        wlist[slot + 2 * j]     = (b << 28) | (0u << 26) | (cellw << 11) | j;
        wlist[slot + 2 * j + 1] = (b << 28) | (1u << 26) | (cellw << 11) | j;
      }
    } else {         // P grid: task 2 (vs T)
      unsigned slot = atomicAdd(&wcnt[4], nch);
      for (unsigned j = 0; j < nch; ++j)
        wlist[slot + j] = (b << 28) | (2u << 26) | (cellw << 11) | j;
    }
  }
}

__global__ __launch_bounds__(256) void scatter_kernel(
    const float* __restrict__ yp, const float* __restrict__ yt,
    const unsigned* __restrict__ pack, const int* __restrict__ pflat,
    const unsigned* __restrict__ prank, float4* __restrict__ sorted) {
  int t = blockIdx.x * 256 + threadIdx.x;
  const float* src;
  int row;
  if (t < NROWS) { row = t; src = yp + 3 * t; }
  else { row = t - NROWS; src = yt + 3 * row; }
  unsigned pos = (pack[pflat[t]] >> 14) + prank[t];
  sorted[pos] = make_float4(src[0], src[1], src[2], __int_as_float(row));
}

// ---------- queries: persistent waves, claim-based, points staged in LDS --
// Each wave claims a (batch,task,cell,chunk) item, enumerates the cell
// neighborhood ONCE loading candidate float4s into LDS, then each of the
// <=QC queries scans LDS only. Failed per-query exactness checks append
// (task,row) to the repair worklist.
__global__ __launch_bounds__(256) void query_kernel(
    const float4* __restrict__ sorted, const unsigned* __restrict__ pack,
    unsigned* __restrict__ wcnt, const unsigned* __restrict__ wlist,
    unsigned* __restrict__ rlist,
    float* __restrict__ knnP, float* __restrict__ knnT,
    float* __restrict__ mincol_arr, unsigned* __restrict__ flags) {
  __shared__ unsigned sb[4][3][SEGCAP];     // sS/sC/sP (sP overlaid by cbuf)
  __shared__ float4 bufw[4][CAP];           // staged candidate points (32 KB)
  __shared__ float4 qbw[4][QC];
  const int wave = threadIdx.x >> 6, lane = threadIdx.x & 63;
  unsigned* sS = sb[wave][0];
  unsigned* sC = sb[wave][1];
  unsigned* sP = sb[wave][2];
  float* cbuf = (float*)sb[wave][2];        // epilogue-only (after enum)
  float4* buf = bufw[wave];
  const unsigned nwork = wcnt[4];

  for (;;) {
    unsigned wrk;
    if (lane == 0) wrk = atomicAdd(&wcnt[5], 1u);
    wrk = (unsigned)__shfl((int)wrk, 0, 64);
    if (wrk >= nwork) break;
    const unsigned e = wlist[wrk];
    const int b = (int)((e >> 28) & 1u);
    const int task = (int)((e >> 26) & 3u);
    const int cell = (int)((e >> 11) & 32767u);
    const int qoff = (int)(e & 2047u) * QC;
    const int qg = (task == 2) ? 2 * b : 2 * b + 1;
    const int tg = (task == 0) ? 2 * b : 2 * b + 1;
    const unsigned pc = pack[qg * NCELLS + cell];
    const int cstart = (int)(pc >> 14);
    const int ccnt = (int)(pc & 16383u);
    const int nq = min(QC, ccnt - qoff);
    if (lane < nq) qbw[wave][lane] = sorted[cstart + qoff + lane];
    const int cx = cell & (GRID - 1), cy = (cell >> 5) & (GRID - 1), cz = cell >> 10;
    const int need = (task == 2) ? NEED2 : NEED;

    // ---- enumeration: stage neighborhood candidate points into LDS ----
    int bufcount = 0, M = 0;
    bool overflow = false;
    const int base = tg * NCELLS;
    for (int m = 0; m <= GRID; ++m) {
      const int zlo = max(cz - m, 0), zhi = min(cz + m, GRID - 1);
      const int ylo = max(cy - m, 0), yhi = min(cy + m, GRID - 1);
      const int xlo = max(cx - m, 0), xhi = min(cx + m, GRID - 1);
      const int ny = yhi - ylo + 1;
      const int nrows = (zhi - zlo + 1) * ny;
      for (int rb = 0; rb < nrows && !overflow; rb += 64) {
        const int rho = rb + lane;
        const bool act = rho < nrows;
        const int rr = act ? rho : 0;
        const int z = zlo + rr / ny, y = ylo + rr % ny;
        const int dza = abs(z - cz), dya = abs(y - cy);
        const bool bdry = (dza == m) || (dya == m);
        unsigned stA = 0, cnA = 0, stB = 0, cnB = 0;
        const int rowbase = base + (z * GRID + y) * GRID;
        if (act) {
          if (bdry) {  // full (clamped) x-range: contiguous segment, 2 loads
            unsigned plo = pack[rowbase + xlo];
            unsigned phi = pack[rowbase + xhi];
            stA = plo >> 14;
            cnA = ((phi >> 14) + (phi & 16383u)) - stA;
          } else {     // interior row: only the two new x = cx +- m cells
            int xl = cx - m, xr = cx + m;
            if (xl >= 0) { unsigned p = pack[rowbase + xl]; stA = p >> 14; cnA = p & 16383u; }
            if (xr < GRID) { unsigned p = pack[rowbase + xr]; stB = p >> 14; cnB = p & 16383u; }
          }
        }
        unsigned long long mA = __ballot(cnA > 0);
        unsigned long long mB = __ballot(cnB > 0);
        int nA = __popcll(mA);
        int nseg = nA + __popcll(mB);
        if (nseg == 0) continue;
        int slA = lanerank(mA), slB = nA + lanerank(mB);
        if (cnA > 0) { sS[slA] = stA; sC[slA] = cnA; }
        if (cnB > 0) { sS[slB] = stB; sC[slB] = cnB; }
        unsigned total = 0;
        for (int h = 0; h < 2; ++h) {
          int sl = h * 64 + lane;
          unsigned v = (sl < nseg) ? sC[sl] : 0u;
          unsigned inc = v;
#pragma unroll
          for (int s2 = 1; s2 < 64; s2 <<= 1) {
            unsigned t2 = __shfl_up(inc, s2, 64);
            if (lane >= s2) inc += t2;
          }
          if (sl < nseg) sP[sl] = total + inc - v;
          total += __shfl(inc, 63, 64);
          if (nseg <= 64) break;
        }
        int sh0 = (nseg > 1) ? (1 << (31 - __clz(nseg - 1))) : 0;
        for (unsigned cb = 0; cb < total; cb += 64) {
          unsigned c = cb + (unsigned)lane;
          if (c < total && (int)c + bufcount < CAP) {
            int lo = 0;
            for (int sh = sh0; sh; sh >>= 1) {
              int mid = lo + sh;
              if (mid < nseg && sP[mid] <= c) lo = mid;
            }
            buf[bufcount + (int)c] = sorted[sS[lo] + (c - sP[lo])];
          }
        }
        bufcount += (int)total;
        if (bufcount > CAP) overflow = true;
      }
      if (overflow) break;
      M = m;
      bool covered = (zlo == 0 && zhi == GRID - 1 && ylo == 0 && yhi == GRID - 1 &&
                      xlo == 0 && xhi == GRID - 1);
      if (covered || (m >= 1 && bufcount >= need)) break;
    }

    // ---- per-query scan of the LDS point buffer ----
    const float mh = (float)M * H;
    for (int j = 0; j < nq; ++j) {
      float4 q = qbw[wave][j];
      const int row = __float_as_int(q.w);
      float fx = fminf(q.x - (RLO + cx * H), (RLO + (cx + 1) * H) - q.x);
      float fy = fminf(q.y - (RLO + cy * H), (RLO + (cy + 1) * H) - q.y);
      float fz = fminf(q.z - (RLO + cz * H), (RLO + (cz + 1) * H) - q.z);
      float fq = fminf(fx, fminf(fy, fz));   // may be <0 for clamped queries
      float bnd = fmaxf(mh + fq, 0.0f) * 0.999f;
      float bnd2 = bnd * bnd;
      bool bad;
      if (task < 2) {
        float a[KC];
#pragma unroll
        for (int k = 0; k < KC; ++k) a[k] = INFINITY;
        float dmin = INFINITY;
        bool act = lane < bufcount;
        float4 p = buf[act ? lane : 0];
        for (int cb = 0; cb < bufcount; cb += 64) {
          int pos2 = cb + 64 + lane;
          bool act2 = pos2 < bufcount;
          float4 p2 = buf[act2 ? pos2 : 0];        // prefetch next batch
          float d = act ? sqd3(q.x, q.y, q.z, p) : INFINITY;
          dmin = fminf(dmin, fmaxf(d, a[KC - 1])); // exact evicted-value track
          insertK(a, d);
          p = p2; act = act2;
        }
        int cntq = 0;
#pragma unroll
        for (int k = 0; k < KC; ++k) cntq += (a[k] <= bnd2) ? 1 : 0;
#pragma unroll
        for (int s2 = 1; s2 < 64; s2 <<= 1) cntq += __shfl_xor(cntq, s2, 64);
        float tau;
        if (cntq >= KNN && cntq <= 64) {
          tau = bnd2;
        } else {
          float slm = bitonic_sort64(a[0], lane);  // lane minima never truncated
          tau = __shfl(slm, 15, 64);
        }
        int tot = 0;
        int idxk[KC];
#pragma unroll
        for (int k = 0; k < KC; ++k) {
          unsigned long long mk = __ballot(a[k] <= tau);
          idxk[k] = tot + lanerank(mk);
          tot += __popcll(mk);
        }
#pragma unroll
        for (int k = 0; k < KC; ++k)
          if (a[k] <= tau && idxk[k] < 64) cbuf[idxk[k]] = a[k];
        float v = (lane < tot) ? cbuf[lane] : INFINITY;  // same-wave: no barrier
        v = bitonic_sort64(v, lane);
        float f15 = __shfl(v, 15, 64);
        // EXACT validity: truncation loss, compaction overflow, insufficient
        // shell coverage, buffer overflow.
        bad = overflow || (tot > 64) || (__ballot(dmin <= f15) != 0ull) ||
              (f15 > bnd2);
        float* dst = (task == 0) ? knnP : knnT;
        if (lane < KNN) dst[row * KNN + lane] = sqrtf(v);
        if (lane == 0) flags[task * NROWS + row] = 0u;  // repair owns residual
      } else {
        float v = INFINITY;
        bool act = lane < bufcount;
        float4 p = buf[act ? lane : 0];
        for (int cb = 0; cb < bufcount; cb += 64) {
          int pos2 = cb + 64 + lane;
          bool act2 = pos2 < bufcount;
          float4 p2 = buf[act2 ? pos2 : 0];
          if (act) v = fminf(v, sqd3(q.x, q.y, q.z, p));
          p = p2; act = act2;
        }
#pragma unroll
        for (int s2 = 1; s2 < 64; s2 <<= 1) v = fminf(v, __shfl_xor(v, s2, 64));
        bad = overflow || (v > bnd2);   // min must lie within proven bound
        if (lane == 0) mincol_arr[row] = sqrtf(v);
      }
      if (lane == 0 && bad) {
        unsigned slot = atomicAdd(&wcnt[6], 1u);
        rlist[slot] = ((unsigned)task << 14) | (unsigned)row;
      }
    }
  }
}

// ---------- parallel repair: claim-based, one wave per flagged (task,row) --
// Re-runs the per-query exact-stop algorithm (guaranteed coverage); only its
// own rare truncation condition leaves a residual flag for combine's dense
// fallback.
__global__ __launch_bounds__(256) void repair_kernel(
    const float* __restrict__ yp, const float* __restrict__ yt,
    const float4* __restrict__ sorted, const unsigned* __restrict__ pack,
    unsigned* __restrict__ wcnt, const unsigned* __restrict__ rlist,
    float* __restrict__ knnP, float* __restrict__ knnT,
    float* __restrict__ mincol_arr, unsigned* __restrict__ flags) {
  __shared__ unsigned sb[4][3][SEGCAP];
  const int wave = threadIdx.x >> 6, lane = threadIdx.x & 63;
  const unsigned nrep = wcnt[6];
  unsigned* sS = sb[wave][0];
  unsigned* sC = sb[wave][1];
  unsigned* sP = sb[wave][2];
  float* cbuf = (float*)sb[wave][2];     // reused after wave_grid_knn_pq
  for (;;) {
    unsigned w;
    if (lane == 0) w = atomicAdd(&wcnt[7], 1u);
    w = (unsigned)__shfl((int)w, 0, 64);
    if (w >= nrep) break;
    const unsigned e = rlist[w];
    const int task = (int)(e >> 14);
    const int row = (int)(e & 16383u);
    const int b = row >> 13;
    const int tg = (task == 0) ? 2 * b : 2 * b + 1;
    const float* q = (task == 2) ? (yp + 3 * row) : (yt + 3 * row);
    const float qx = q[0], qy = q[1], qz = q[2];
    if (task < 2) {
      float a[KC];
#pragma unroll
      for (int k = 0; k < KC; ++k) a[k] = INFINITY;
      float dmin = INFINITY, bnd2;
      int cnt;
      wave_grid_knn_pq<KC, KNN>(tg, qx, qy, qz, sorted, pack, sS, sC, sP,
                                lane, a, dmin, cnt, bnd2);
      float tau;
      if (cnt >= KNN && cnt <= 64) {
        tau = bnd2;
      } else {
        float slm = bitonic_sort64(a[0], lane);
        tau = __shfl(slm, 15, 64);
      }
      int tot = 0;
      int idxk[KC];
#pragma unroll
      for (int k = 0; k < KC; ++k) {
        unsigned long long mk = __ballot(a[k] <= tau);
        idxk[k] = tot + lanerank(mk);
        tot += __popcll(mk);
      }
#pragma unroll
      for (int k = 0; k < KC; ++k)
        if (a[k] <= tau && idxk[k] < 64) cbuf[idxk[k]] = a[k];
      float v = (lane < tot) ? cbuf[lane] : INFINITY;
      v = bitonic_sort64(v, lane);
      float f15 = __shfl(v, 15, 64);
      bool bad = (tot > 64) || (__ballot(dmin <= f15) != 0ull);
      float* dst = (task == 0) ? knnP : knnT;
      if (lane < KNN) dst[row * KNN + lane] = sqrtf(v);
      if (lane == 0) flags[task * NROWS + row] = bad ? 1u : 0u;
    } else {
      float a1[1] = {INFINITY};
      float dmin = INFINITY, bnd2;
      int cnt;
      wave_grid_knn_pq<1, 1>(tg, qx, qy, qz, sorted, pack, sS, sC, sP,
                             lane, a1, dmin, cnt, bnd2);
      float v = a1[0];
#pragma unroll
      for (int s = 1; s < 64; s <<= 1) v = fminf(v, __shfl_xor(v, s, 64));
      if (lane == 0) mincol_arr[row] = sqrtf(v);  // lane minima exact
    }
  }
}

// Guaranteed-exact dense fallback over one grid slice (8192 points):
// lane r (r<16) returns the r-th smallest squared distance.
__device__ float exact16_rowlist(const float4* __restrict__ base,
                                 float qx, float qy, float qz, int lane) {
  float a[KNN];
#pragma unroll
  for (int k = 0; k < KNN; ++k) a[k] = INFINITY;
  for (int s = 0; s < NPTS / 64; ++s) {
    float d = sqd3(qx, qy, qz, base[s * 64 + lane]);
    insertK(a, d);
  }
  float res = INFINITY;
#pragma unroll 1
  for (int r = 0; r < KNN; ++r) {
    float v = a[0];
    int idx = lane;
#pragma unroll
    for (int s = 1; s < 64; s <<= 1) {
      float ov = __shfl_xor(v, s, 64);
      int oi = __shfl_xor(idx, s, 64);
      bool take = (ov < v) || (ov == v && oi < idx);
      v = take ? ov : v;
      idx = take ? oi : idx;
    }
    if (lane == r) res = v;
    if (lane == idx) {
#pragma unroll
      for (int k = 0; k < KNN - 1; ++k) a[k] = a[k + 1];
      a[KNN - 1] = INFINITY;
    }
  }
  return res;
}

// Fused tail+combine: dense-repair residual flagged rows (expected ~0),
// then deterministic double partials.
__global__ __launch_bounds__(256) void combine_kernel(
    const float* __restrict__ yt, const float4* __restrict__ sorted,
    const unsigned* __restrict__ flags, float* __restrict__ knnP,
    float* __restrict__ knnT, const float* __restrict__ mincol_arr,
    double* __restrict__ pd) {
  __shared__ double s1[256], s2[256], s3[256];
  const int t = threadIdx.x, lane = t & 63, wave = t >> 6;
  const int row0 = blockIdx.x * 256;
  const int rbase = row0 + wave * 64;
  unsigned f0 = flags[rbase + lane];
  unsigned f1 = flags[NROWS + rbase + lane];
  unsigned long long m0 = __ballot(f0 != 0u);
  unsigned long long m1 = __ballot(f1 != 0u);
  while (m0) {                                        // wave-uniform loops
    int rr = __ffsll(m0) - 1; m0 &= m0 - 1;
    int row = rbase + rr;
    int bb = row >> 13;
    const float* q = yt + 3 * row;
    float s = exact16_rowlist(sorted + (size_t)(2 * bb) * NPTS, q[0], q[1], q[2], lane);
    if (lane < KNN) knnP[row * KNN + lane] = sqrtf(s);
  }
  while (m1) {
    int rr = __ffsll(m1) - 1; m1 &= m1 - 1;
    int row = rbase + rr;
    int bb = row >> 13;
    const float* q = yt + 3 * row;
    float s = exact16_rowlist(sorted + (size_t)(2 * bb + 1) * NPTS, q[0], q[1], q[2], lane);
    if (lane < KNN) knnT[row * KNN + lane] = sqrtf(s);
  }
  __syncthreads();  // repairs (global writes by this block) visible block-wide
  const int row = row0 + t;
  float s = 0.0f;
#pragma unroll
  for (int k = 0; k < KNN; ++k)
    s += fabsf(knnP[row * KNN + k] - knnT[row * KNN + k]);
  s1[t] = (double)knnP[row * KNN];   // minrow
  s2[t] = (double)mincol_arr[row];
  s3[t] = (double)s;
  __syncthreads();
  for (int off = 128; off > 0; off >>= 1) {
    if (t < off) { s1[t] += s1[t + off]; s2[t] += s2[t + off]; s3[t] += s3[t + off]; }
    __syncthreads();
  }
  if (t == 0) {
    pd[blockIdx.x * 3 + 0] = s1[0];
    pd[blockIdx.x * 3 + 1] = s2[0];
    pd[blockIdx.x * 3 + 2] = s3[0];
  }
}

__global__ __launch_bounds__(64) void finalize_kernel(
    const double* __restrict__ pd, float* __restrict__ out) {
  const int t = threadIdx.x;
  double a = pd[t * 3], b = pd[t * 3 + 1], c = pd[t * 3 + 2];
#pragma unroll
  for (int s = 32; s >= 1; s >>= 1) {
    a += __shfl_down(a, s, 64);
    b += __shfl_down(b, s, 64);
    c += __shfl_down(c, s, 64);
  }
  if (t == 0) {
    double shape = 0.5 * (a + b) / (double)NROWS;
    double dens = c / ((double)NROWS * KNN);
    out[0] = (float)(shape + dens);
    out[1] = (float)shape;
    out[2] = (float)dens;
  }
}

extern "C" void kernel_launch(void* const* d_in, const int* in_sizes, int n_in,
                              void* d_out, int out_size, void* d_ws, size_t ws_size,
                              hipStream_t stream) {
  (void)in_sizes; (void)n_in; (void)out_size; (void)ws_size;
  const float* yp = (const float*)d_in[0];  // y_pred [B, N, 3]
  const float* yt = (const float*)d_in[1];  // y_true [B, N, 3]
  char* w = (char*)d_ws;
  unsigned* counts  = (unsigned*)w;  w += TOTCELLS * 4;       // 512 KB
  unsigned* partial = (unsigned*)w;  w += TOTCELLS * 4;       // 512 KB
  unsigned* aux     = (unsigned*)w;  w += 512;
  unsigned* pack    = (unsigned*)w;  w += TOTCELLS * 4;       // 512 KB
  int*      pflat   = (int*)w;       w += 2 * NROWS * 4;      // 128 KB
  unsigned* prank   = (unsigned*)w;  w += 2 * NROWS * 4;      // 128 KB
  float4*   sorted  = (float4*)w;    w += 2 * NROWS * 16;     // 1 MB
  float*    knnP    = (float*)w;     w += NROWS * KNN * 4;    // 1 MB
  float*    knnT    = (float*)w;     w += NROWS * KNN * 4;    // 1 MB
  float*    mincol  = (float*)w;     w += NROWS * 4;
  unsigned* flags   = (unsigned*)w;  w += 2 * NROWS * 4;      // tasks 0/1 only
  double*   pd      = (double*)w;    w += 64 * 3 * 8;
  unsigned* wcnt    = (unsigned*)w;  w += 64;
  unsigned* wlist   = (unsigned*)w;  w += WLCAP * 4;          // 192 KB
  unsigned* rlist   = (unsigned*)w;  w += 3 * NROWS * 4;      // 192 KB
  float* out = (float*)d_out;

  hipMemsetAsync(counts, 0, (size_t)TOTCELLS * 4, stream);
  count_kernel<<<2 * NROWS / 256, 256, 0, stream>>>(yp, yt, counts, pflat, prank, wcnt);
  scan1_kernel<<<SCAN_BLOCKS, 1024, 0, stream>>>(counts, partial, aux);
  pack_kernel<<<SCAN_BLOCKS, 1024, 0, stream>>>(counts, partial, aux, pack, wcnt, wlist);
  scatter_kernel<<<2 * NROWS / 256, 256, 0, stream>>>(yp, yt, pack, pflat, prank, sorted);
  query_kernel<<<1024, 256, 0, stream>>>(sorted, pack, wcnt, wlist, rlist,
                                         knnP, knnT, mincol, flags);
  repair_kernel<<<256, 256, 0, stream>>>(yp, yt, sorted, pack, wcnt, rlist,
                                         knnP, knnT, mincol, flags);
  combine_kernel<<<64, 256, 0, stream>>>(yt, sorted, flags, knnP, knnT, mincol, pd);
  finalize_kernel<<<1, 64, 0, stream>>>(pd, out);
}

// Round 5
// 154.535 us; speedup vs baseline: 3.2830x; 3.2830x over previous
//
#include <hip/hip_runtime.h>
#include <math.h>

#define NPTS 8192
#define NB 2
#define NROWS (NB * NPTS)
#define KNN 16
#define KC 6          // per-lane kept candidates (truncated sorted list)

// Spatial grid: 32^3 cells of width H. 4 grids: P/T x batch. g: P=2b, T=2b+1.
#define GRID 32
#define NCELLS (GRID * GRID * GRID)        // 32768
#define TOTCELLS (4 * NCELLS)              // 131072
#define H 0.35f
#define RLO (-5.6f)
#define INVH (1.0f / H)
#define SCAN_BLOCKS 128
#define SEGCAP 132                          // >= 2*64 segments per row-chunk

// QC co-celled queries share one wave's enumeration stream (registers only;
// R0 memory structure preserved). Worklist = (batch,task,cell,chunk) items.
#define QC 3
#define WLCAP 49152     // sum over grids/tasks of ceil(cnt/QC) <= 6*8192
#define QBLOCKS 2048

__device__ __forceinline__ int cellof(float x) {
  int c = (int)floorf((x - RLO) * INVH);
  return min(max(c, 0), GRID - 1);
}

__device__ __forceinline__ float sqd3(float qx, float qy, float qz, float4 c) {
  float dx = qx - c.x, dy = qy - c.y, dz = qz - c.z;
  return fmaf(dx, dx, fmaf(dy, dy, dz * dz));
}

__device__ __forceinline__ int lanerank(unsigned long long mk) {
  return __builtin_amdgcn_mbcnt_hi((unsigned)(mk >> 32),
                                   __builtin_amdgcn_mbcnt_lo((unsigned)mk, 0));
}

// Guarded insert into ascending sorted-K list (per-lane).
template <int K>
__device__ __forceinline__ void insertK(float (&a)[K], float d) {
  if (d < a[K - 1]) {
    a[K - 1] = d;
#pragma unroll
    for (int k = K - 1; k > 0; --k) {
      float lo = fminf(a[k - 1], a[k]);
      a[k] = fmaxf(a[k - 1], a[k]);
      a[k - 1] = lo;
    }
  }
}

// Full ascending bitonic sort of one value per lane across the 64-lane wave.
__device__ __forceinline__ float bitonic_sort64(float v, int lane) {
#pragma unroll
  for (int k = 2; k <= 64; k <<= 1) {
#pragma unroll
    for (int j = k >> 1; j >= 1; j >>= 1) {
      float o = __shfl_xor(v, j, 64);
      bool up = ((lane & k) == 0);
      bool lower = ((lane & j) == 0);
      float mn = fminf(v, o), mx = fmaxf(v, o);
      v = (up == lower) ? mn : mx;
    }
  }
  return v;
}

// Wave-cooperative kNN for QC co-celled queries (R0 enumeration structure:
// streaming candidates from global, one query-batch of candidates per 64
// lanes, expanding Chebyshev shells on the counting-sorted grid).
// Exactness per query q: after completing shell m, an unvisited point is
// > (m*H + fq[q]) away (fq = min per-axis in-cell slack, clamped >= 0 for
// out-of-range queries). Stop when ALL QC queries have >= NEEDQ kept
// candidates within their bound (duplicated tail queries mirror q0, so they
// never delay the stop). dmin[q] = min value ever not-kept (exact truncation
// test by caller). cnt/bnd2 returned from the final stop test.
template <int K, int NEEDQ>
__device__ __forceinline__ void wave_grid_knn_q(
    int g, int cx, int cy, int cz,
    const float (&qx)[QC], const float (&qy)[QC], const float (&qz)[QC],
    const float4* __restrict__ sorted, const unsigned* __restrict__ pack,
    unsigned* sS, unsigned* sC, unsigned* sPre, int lane,
    float (&a)[QC][K], float (&dminq)[QC], int (&cntq)[QC],
    float (&bnd2q)[QC]) {
  float fq[QC];
#pragma unroll
  for (int q = 0; q < QC; ++q) {
    float fx = fminf(qx[q] - (RLO + cx * H), (RLO + (cx + 1) * H) - qx[q]);
    float fy = fminf(qy[q] - (RLO + cy * H), (RLO + (cy + 1) * H) - qy[q]);
    float fz = fminf(qz[q] - (RLO + cz * H), (RLO + (cz + 1) * H) - qz[q]);
    fq[q] = fminf(fx, fminf(fy, fz));      // may be <0 for clamped queries
  }
  const int base = g * NCELLS;
  for (int m = 0; m <= GRID; ++m) {
    const int zlo = max(cz - m, 0), zhi = min(cz + m, GRID - 1);
    const int ylo = max(cy - m, 0), yhi = min(cy + m, GRID - 1);
    const int xlo = max(cx - m, 0), xhi = min(cx + m, GRID - 1);
    const int ny = yhi - ylo + 1;
    const int nrows = (zhi - zlo + 1) * ny;
    for (int rb = 0; rb < nrows; rb += 64) {
      const int rho = rb + lane;
      const bool act = rho < nrows;
      const int rr = act ? rho : 0;
      const int z = zlo + rr / ny, y = ylo + rr % ny;
      const int dza = abs(z - cz), dya = abs(y - cy);
      const bool bdry = (dza == m) || (dya == m);
      unsigned stA = 0, cnA = 0, stB = 0, cnB = 0;
      const int rowbase = base + (z * GRID + y) * GRID;
      if (act) {
        if (bdry) {  // full (clamped) x-range: contiguous segment, 2 loads
          unsigned plo = pack[rowbase + xlo];
          unsigned phi = pack[rowbase + xhi];
          stA = plo >> 14;
          cnA = ((phi >> 14) + (phi & 16383u)) - stA;
        } else {     // interior row: only the two new x = cx +- m cells
          int xl = cx - m, xr = cx + m;
          if (xl >= 0) { unsigned p = pack[rowbase + xl]; stA = p >> 14; cnA = p & 16383u; }
          if (xr < GRID) { unsigned p = pack[rowbase + xr]; stB = p >> 14; cnB = p & 16383u; }
        }
      }
      // ballot-compact nonempty segments into wave-private LDS
      unsigned long long mA = __ballot(cnA > 0);
      unsigned long long mB = __ballot(cnB > 0);
      int nA = __popcll(mA);
      int nseg = nA + __popcll(mB);
      if (nseg == 0) continue;
      int slA = lanerank(mA), slB = nA + lanerank(mB);
      if (cnA > 0) { sS[slA] = stA; sC[slA] = cnA; }
      if (cnB > 0) { sS[slB] = stB; sC[slB] = cnB; }
      // exclusive prefix over segment counts (<=128 segs, 2 halves of 64)
      unsigned total = 0;
      for (int h = 0; h < 2; ++h) {
        int sl = h * 64 + lane;
        unsigned v = (sl < nseg) ? sC[sl] : 0u;
        unsigned inc = v;
#pragma unroll
        for (int s2 = 1; s2 < 64; s2 <<= 1) {
          unsigned t = __shfl_up(inc, s2, 64);
          if (lane >= s2) inc += t;
        }
        if (sl < nseg) sPre[sl] = total + inc - v;
        total += __shfl(inc, 63, 64);
        if (nseg <= 64) break;
      }
      // candidates 64-wide across segment boundaries; depth-adaptive search
      int sh0 = (nseg > 1) ? (1 << (31 - __clz(nseg - 1))) : 0;
      for (unsigned cb = 0; cb < total; cb += 64) {
        unsigned c = cb + (unsigned)lane;
        bool cact = c < total;
        unsigned cc = cact ? c : (total - 1);
        int lo = 0;  // max seg with sPre[seg] <= cc (sPre[0]==0)
        for (int sh = sh0; sh; sh >>= 1) {
          int mid = lo + sh;
          if (mid < nseg && sPre[mid] <= cc) lo = mid;
        }
        float4 p = sorted[sS[lo] + (cc - sPre[lo])];
#pragma unroll
        for (int q = 0; q < QC; ++q) {
          float d = cact ? sqd3(qx[q], qy[q], qz[q], p) : INFINITY;
          dminq[q] = fminf(dminq[q], fmaxf(d, a[q][K - 1]));
          insertK(a[q], d);
        }
      }
    }
    // stop test: all queries have >= NEEDQ kept candidates within bound
#pragma unroll
    for (int q = 0; q < QC; ++q) {
      float bnd = fmaxf((float)m * H + fq[q], 0.0f) * 0.999f;
      bnd2q[q] = bnd * bnd;
    }
    int cpA = 0, cpB = 0;          // pack counts: q0 | q1<<16, q2
#pragma unroll
    for (int k = 0; k < K; ++k) {
      cpA += (a[0][k] <= bnd2q[0] ? 1 : 0) + (a[1][k] <= bnd2q[1] ? 65536 : 0);
      cpB += (a[2][k] <= bnd2q[2] ? 1 : 0);
    }
#pragma unroll
    for (int s2 = 1; s2 < 64; s2 <<= 1) {
      cpA += __shfl_xor(cpA, s2, 64);
      cpB += __shfl_xor(cpB, s2, 64);
    }
    cntq[0] = cpA & 0xffff;
    cntq[1] = cpA >> 16;
    cntq[2] = cpB;
    bool okall = (cntq[0] >= NEEDQ) && (cntq[1] >= NEEDQ) && (cntq[2] >= NEEDQ);
    bool covered = (zlo == 0 && zhi == GRID - 1 && ylo == 0 && yhi == GRID - 1 &&
                    xlo == 0 && xhi == GRID - 1);
    if (okall || covered) break;
  }
}

// ---------- build ----------
__global__ __launch_bounds__(256) void count_kernel(
    const float* __restrict__ yp, const float* __restrict__ yt,
    unsigned* __restrict__ counts, int* __restrict__ pflat,
    unsigned* __restrict__ prank, unsigned* __restrict__ wcnt) {
  if (blockIdx.x == 0 && threadIdx.x < 8) wcnt[threadIdx.x] = 0;  // before pack
  int t = blockIdx.x * 256 + threadIdx.x;          // 0 .. 2*NROWS-1
  const float* src;
  int g;
  if (t < NROWS) { src = yp + 3 * t; g = 2 * (t >> 13); }
  else { int u = t - NROWS; src = yt + 3 * u; g = 2 * (u >> 13) + 1; }
  int flat = g * NCELLS + (cellof(src[2]) * GRID + cellof(src[1])) * GRID + cellof(src[0]);
  unsigned r = atomicAdd(&counts[flat], 1u);
  pflat[t] = flat;
  prank[t] = r;
}

__global__ __launch_bounds__(1024) void scan1_kernel(
    const unsigned* __restrict__ counts, unsigned* __restrict__ partial,
    unsigned* __restrict__ aux) {
  __shared__ unsigned ws[16];
  const int t = threadIdx.x, lane = t & 63, wave = t >> 6;
  const int tid = blockIdx.x * 1024 + t;
  unsigned v = counts[tid];
  unsigned inc = v;
#pragma unroll
  for (int off = 1; off < 64; off <<= 1) {
    unsigned u = __shfl_up(inc, off, 64);
    if (lane >= off) inc += u;
  }
  if (lane == 63) ws[wave] = inc;
  __syncthreads();
  unsigned wex = 0;
  if (wave == 0) {
    unsigned o = (lane < 16) ? ws[lane] : 0u;
    unsigned wi = o;
#pragma unroll
    for (int off = 1; off < 16; off <<= 1) {
      unsigned u = __shfl_up(wi, off, 64);
      if (lane >= off) wi += u;
    }
    if (lane < 16) ws[lane] = wi - o;
  }
  __syncthreads();
  wex = ws[wave];
  partial[tid] = wex + inc - v;
  if (t == 1023) aux[blockIdx.x] = wex + inc;
}

// Fused scan2+pack + flat (batch,task,cell,chunk) worklist build.
// cellinfo pack: global start (<=16b used of 18) << 14 | count (14b)
// worklist entry: b<<30 | task<<28 | cell<<13 | chunk_j (j <= 5461 fits 13b)
__global__ __launch_bounds__(1024) void pack_kernel(
    const unsigned* __restrict__ counts, const unsigned* __restrict__ partial,
    const unsigned* __restrict__ aux, unsigned* __restrict__ pack,
    unsigned* __restrict__ wcnt, unsigned* __restrict__ wlist) {
  __shared__ unsigned sa[2];
  const int t = threadIdx.x;
  if (t < 128) {
    unsigned v = (t < (int)blockIdx.x) ? aux[t] : 0u;
#pragma unroll
    for (int s = 1; s < 64; s <<= 1) v += __shfl_xor(v, s, 64);
    if ((t & 63) == 0) sa[t >> 6] = v;
  }
  __syncthreads();
  unsigned base = sa[0] + sa[1];
  int i = blockIdx.x * 1024 + t;
  unsigned cnti = counts[i];
  pack[i] = ((partial[i] + base) << 14) | cnti;
  if (cnti > 0) {
    int g = i >> 15;                 // NCELLS = 2^15
    unsigned b = (unsigned)(g >> 1);
    unsigned cellw = (unsigned)(i & (NCELLS - 1));
    unsigned nch = (cnti + QC - 1) / QC;
    if (g & 1) {     // T grid: tasks 0 (vs P) and 1 (vs T)
      unsigned slot = atomicAdd(&wcnt[4], 2 * nch);
      for (unsigned j = 0; j < nch; ++j) {
        wlist[slot + 2 * j]     = (b << 30) | (0u << 28) | (cellw << 13) | j;
        wlist[slot + 2 * j + 1] = (b << 30) | (1u << 28) | (cellw << 13) | j;
      }
    } else {         // P grid: task 2 (vs T)
      unsigned slot = atomicAdd(&wcnt[4], nch);
      for (unsigned j = 0; j < nch; ++j)
        wlist[slot + j] = (b << 30) | (2u << 28) | (cellw << 13) | j;
    }
  }
}

__global__ __launch_bounds__(256) void scatter_kernel(
    const float* __restrict__ yp, const float* __restrict__ yt,
    const unsigned* __restrict__ pack, const int* __restrict__ pflat,
    const unsigned* __restrict__ prank, float4* __restrict__ sorted) {
  int t = blockIdx.x * 256 + threadIdx.x;
  const float* src;
  int row;
  if (t < NROWS) { row = t; src = yp + 3 * t; }
  else { row = t - NROWS; src = yt + 3 * row; }
  unsigned pos = (pack[pflat[t]] >> 14) + prank[t];
  sorted[pos] = make_float4(src[0], src[1], src[2], __int_as_float(row));
}

// ---------- queries: one wave per (cell,task,chunk of QC queries) ----------
// Persistent static-stride over the flat worklist; R0 streaming enumeration
// shared by up to QC co-celled queries held in registers. task 0: T vs P
// grid -> knnP + flag; task 1: T vs T -> knnT + flag; task 2: P vs T ->
// mincol (exact, no flag).
__global__ __launch_bounds__(256) void query_kernel(
    const float4* __restrict__ sorted, const unsigned* __restrict__ pack,
    const unsigned* __restrict__ wcnt, const unsigned* __restrict__ wlist,
    float* __restrict__ knnP, float* __restrict__ knnT,
    float* __restrict__ mincol_arr, unsigned* __restrict__ flags) {
  __shared__ unsigned sb[4][3][SEGCAP];
  __shared__ float cbw[4][64];
  const int wave = threadIdx.x >> 6, lane = threadIdx.x & 63;
  unsigned* sS = sb[wave][0];
  unsigned* sC = sb[wave][1];
  unsigned* sP = sb[wave][2];
  float* cbuf = cbw[wave];
  const unsigned nwork = wcnt[4];
  const unsigned nw = gridDim.x * 4;
  for (unsigned wrk = blockIdx.x * 4 + wave; wrk < nwork; wrk += nw) {
    const unsigned e = wlist[wrk];
    const int b = (int)((e >> 30) & 1u);
    const int task = (int)((e >> 28) & 3u);
    const int cell = (int)((e >> 13) & 32767u);
    const int qoff = (int)(e & 8191u) * QC;
    const int qg = (task == 2) ? 2 * b : 2 * b + 1;
    const int tg = (task == 0) ? 2 * b : 2 * b + 1;
    const unsigned pc = pack[qg * NCELLS + cell];
    const int cstart = (int)(pc >> 14);
    const int ccnt = (int)(pc & 16383u);
    const int nq = min(QC, ccnt - qoff);
    const int cx = cell & (GRID - 1), cy = (cell >> 5) & (GRID - 1), cz = cell >> 10;

    float qx[QC], qy[QC], qz[QC];
    int rowq[QC];
#pragma unroll
    for (int q = 0; q < QC; ++q) {   // duplicate last query into empty slots
      float4 eq = sorted[cstart + qoff + min(q, nq - 1)];
      qx[q] = eq.x; qy[q] = eq.y; qz[q] = eq.z;
      rowq[q] = __float_as_int(eq.w);
    }

    if (task < 2) {
      float a[QC][KC];
      float dminq[QC];
#pragma unroll
      for (int q = 0; q < QC; ++q) {
        dminq[q] = INFINITY;
#pragma unroll
        for (int k = 0; k < KC; ++k) a[q][k] = INFINITY;
      }
      int cntq[QC];
      float bnd2q[QC];
      wave_grid_knn_q<KC, KNN>(tg, cx, cy, cz, qx, qy, qz, sorted, pack,
                               sS, sC, sP, lane, a, dminq, cntq, bnd2q);
      float* dstbase = (task == 0) ? knnP : knnT;
#pragma unroll
      for (int q = 0; q < QC; ++q) {
        if (q >= nq) break;                      // wave-uniform
        // Compaction threshold tau (>= true v16, with <=64 kept <= tau):
        float tau;
        if (cntq[q] >= KNN && cntq[q] <= 64) {
          tau = bnd2q[q];
        } else {
          float slm = bitonic_sort64(a[q][0], lane);  // lane minima never lost
          tau = __shfl(slm, 15, 64);
        }
        int tot = 0;
        int idxk[KC];
#pragma unroll
        for (int k = 0; k < KC; ++k) {
          unsigned long long mk = __ballot(a[q][k] <= tau);
          idxk[k] = tot + lanerank(mk);
          tot += __popcll(mk);
        }
#pragma unroll
        for (int k = 0; k < KC; ++k)
          if (a[q][k] <= tau && idxk[k] < 64) cbuf[idxk[k]] = a[q][k];
        float v = (lane < tot) ? cbuf[lane] : INFINITY;  // same-wave: no barrier
        v = bitonic_sort64(v, lane);
        float f15 = __shfl(v, 15, 64);
        // EXACT validity: a lost top-16 member implies dmin <= v16 <= f15.
        bool bad = (tot > 64) || (__ballot(dminq[q] <= f15) != 0ull);
        if (lane < KNN) dstbase[rowq[q] * KNN + lane] = sqrtf(v);
        if (lane == 0) flags[task * NROWS + rowq[q]] = bad ? 1u : 0u;
      }
    } else {
      float a1[QC][1];
      float dminq[QC];
#pragma unroll
      for (int q = 0; q < QC; ++q) { a1[q][0] = INFINITY; dminq[q] = INFINITY; }
      int cntq[QC];
      float bnd2q[QC];
      wave_grid_knn_q<1, 1>(tg, cx, cy, cz, qx, qy, qz, sorted, pack,
                            sS, sC, sP, lane, a1, dminq, cntq, bnd2q);
#pragma unroll
      for (int q = 0; q < QC; ++q) {
        if (q >= nq) break;
        float v = a1[q][0];
#pragma unroll
        for (int s2 = 1; s2 < 64; s2 <<= 1) v = fminf(v, __shfl_xor(v, s2, 64));
        if (lane == 0) mincol_arr[rowq[q]] = sqrtf(v);  // lane minima exact
      }
    }
  }
}

// Guaranteed-exact dense fallback over one grid slice (8192 points):
// lane r (r<16) returns the r-th smallest squared distance.
__device__ float exact16_rowlist(const float4* __restrict__ base,
                                 float qx, float qy, float qz, int lane) {
  float a[KNN];
#pragma unroll
  for (int k = 0; k < KNN; ++k) a[k] = INFINITY;
  for (int s = 0; s < NPTS / 64; ++s) {
    float d = sqd3(qx, qy, qz, base[s * 64 + lane]);
    insertK(a, d);
  }
  float res = INFINITY;
#pragma unroll 1
  for (int r = 0; r < KNN; ++r) {
    float v = a[0];
    int idx = lane;
#pragma unroll
    for (int s = 1; s < 64; s <<= 1) {
      float ov = __shfl_xor(v, s, 64);
      int oi = __shfl_xor(idx, s, 64);
      bool take = (ov < v) || (ov == v && oi < idx);
      v = take ? ov : v;
      idx = take ? oi : idx;
    }
    if (lane == r) res = v;
    if (lane == idx) {
#pragma unroll
      for (int k = 0; k < KNN - 1; ++k) a[k] = a[k + 1];
      a[KNN - 1] = INFINITY;
    }
  }
  return res;
}

// Fused tail+combine: each wave repairs flagged rows among its 64 rows
// (expected ~0 per launch: flag needs one lane holding >=7 of a top-16),
// then the block computes deterministic double partials.
__global__ __launch_bounds__(256) void combine_kernel(
    const float* __restrict__ yt, const float4* __restrict__ sorted,
    const unsigned* __restrict__ flags, float* __restrict__ knnP,
    float* __restrict__ knnT, const float* __restrict__ mincol_arr,
    double* __restrict__ pd) {
  __shared__ double s1[256], s2[256], s3[256];
  const int t = threadIdx.x, lane = t & 63, wave = t >> 6;
  const int row0 = blockIdx.x * 256;
  const int rbase = row0 + wave * 64;
  unsigned f0 = flags[rbase + lane];
  unsigned f1 = flags[NROWS + rbase + lane];
  unsigned long long m0 = __ballot(f0 != 0u);
  unsigned long long m1 = __ballot(f1 != 0u);
  while (m0) {                                        // wave-uniform loop
    int rr = __ffsll(m0) - 1; m0 &= m0 - 1;
    int row = rbase + rr;
    int bb = row >> 13;
    const float* q = yt + 3 * row;
    float s = exact16_rowlist(sorted + (size_t)(2 * bb) * NPTS, q[0], q[1], q[2], lane);
    if (lane < KNN) knnP[row * KNN + lane] = sqrtf(s);
  }
  while (m1) {
    int rr = __ffsll(m1) - 1; m1 &= m1 - 1;
    int row = rbase + rr;
    int bb = row >> 13;
    const float* q = yt + 3 * row;
    float s = exact16_rowlist(sorted + (size_t)(2 * bb + 1) * NPTS, q[0], q[1], q[2], lane);
    if (lane < KNN) knnT[row * KNN + lane] = sqrtf(s);
  }
  __syncthreads();  // repairs (global writes by this block) visible block-wide
  const int row = row0 + t;
  float s = 0.0f;
#pragma unroll
  for (int k = 0; k < KNN; ++k)
    s += fabsf(knnP[row * KNN + k] - knnT[row * KNN + k]);
  s1[t] = (double)knnP[row * KNN];   // minrow
  s2[t] = (double)mincol_arr[row];
  s3[t] = (double)s;
  __syncthreads();
  for (int off = 128; off > 0; off >>= 1) {
    if (t < off) { s1[t] += s1[t + off]; s2[t] += s2[t + off]; s3[t] += s3[t + off]; }
    __syncthreads();
  }
  if (t == 0) {
    pd[blockIdx.x * 3 + 0] = s1[0];
    pd[blockIdx.x * 3 + 1] = s2[0];
    pd[blockIdx.x * 3 + 2] = s3[0];
  }
}

__global__ __launch_bounds__(64) void finalize_kernel(
    const double* __restrict__ pd, float* __restrict__ out) {
  const int t = threadIdx.x;
  double a = pd[t * 3], b = pd[t * 3 + 1], c = pd[t * 3 + 2];
#pragma unroll
  for (int s = 32; s >= 1; s >>= 1) {
    a += __shfl_down(a, s, 64);
    b += __shfl_down(b, s, 64);
    c += __shfl_down(c, s, 64);
  }
  if (t == 0) {
    double shape = 0.5 * (a + b) / (double)NROWS;
    double dens = c / ((double)NROWS * KNN);
    out[0] = (float)(shape + dens);
    out[1] = (float)shape;
    out[2] = (float)dens;
  }
}

extern "C" void kernel_launch(void* const* d_in, const int* in_sizes, int n_in,
                              void* d_out, int out_size, void* d_ws, size_t ws_size,
                              hipStream_t stream) {
  (void)in_sizes; (void)n_in; (void)out_size; (void)ws_size;
  const float* yp = (const float*)d_in[0];  // y_pred [B, N, 3]
  const float* yt = (const float*)d_in[1];  // y_true [B, N, 3]
  char* w = (char*)d_ws;
  unsigned* counts  = (unsigned*)w;  w += TOTCELLS * 4;       // 512 KB
  unsigned* partial = (unsigned*)w;  w += TOTCELLS * 4;       // 512 KB
  unsigned* aux     = (unsigned*)w;  w += 512;
  unsigned* pack    = (unsigned*)w;  w += TOTCELLS * 4;       // 512 KB
  int*      pflat   = (int*)w;       w += 2 * NROWS * 4;      // 128 KB
  unsigned* prank   = (unsigned*)w;  w += 2 * NROWS * 4;      // 128 KB
  float4*   sorted  = (float4*)w;    w += 2 * NROWS * 16;     // 1 MB
  float*    knnP    = (float*)w;     w += NROWS * KNN * 4;    // 1 MB
  float*    knnT    = (float*)w;     w += NROWS * KNN * 4;    // 1 MB
  float*    mincol  = (float*)w;     w += NROWS * 4;
  unsigned* flags   = (unsigned*)w;  w += 2 * NROWS * 4;      // written every launch
  double*   pd      = (double*)w;    w += 64 * 3 * 8;
  unsigned* wcnt    = (unsigned*)w;  w += 64;                 // [4] = item count
  unsigned* wlist   = (unsigned*)w;  w += WLCAP * 4;          // 192 KB
  float* out = (float*)d_out;

  hipMemsetAsync(counts, 0, (size_t)TOTCELLS * 4, stream);
  count_kernel<<<2 * NROWS / 256, 256, 0, stream>>>(yp, yt, counts, pflat, prank, wcnt);
  scan1_kernel<<<SCAN_BLOCKS, 1024, 0, stream>>>(counts, partial, aux);
  pack_kernel<<<SCAN_BLOCKS, 1024, 0, stream>>>(counts, partial, aux, pack, wcnt, wlist);
  scatter_kernel<<<2 * NROWS / 256, 256, 0, stream>>>(yp, yt, pack, pflat, prank, sorted);
  query_kernel<<<QBLOCKS, 256, 0, stream>>>(sorted, pack, wcnt, wlist,
                                            knnP, knnT, mincol, flags);
  combine_kernel<<<64, 256, 0, stream>>>(yt, sorted, flags, knnP, knnT, mincol, pd);
  finalize_kernel<<<1, 64, 0, stream>>>(pd, out);
}